// Round 1
// baseline (8195.966 us; speedup 1.0000x reference)
//
#include <hip/hip_runtime.h>
#include <hip/hip_bf16.h>

// WindowAttentionLite: x(4,256,256,256) fp32, w_qkv(768,256), w_proj(256,256)
// WINDOW=8 -> 64 tokens/window, NUM_HEADS=8, head_dim=32, no padding (256%8==0).
// One block per window, fully fused (QKV -> attn -> proj), no workspace.

#define DIMC  256
#define NH    8
#define HD    32
#define WS    8
#define NTOK  64
#define HRES  256

__global__ __launch_bounds__(512, 1)
void win_attn_fused(const float* __restrict__ x,
                    const float* __restrict__ w_qkv,
                    const float* __restrict__ w_proj,
                    float* __restrict__ out)
{
    // LDS ~69.3 KB -> 2 blocks/CU
    __shared__ __hip_bfloat16 x_s[DIMC][NTOK];      // [c][px]   32 KB
    __shared__ __hip_bfloat16 q_s[NTOK][HD + 2];    // [tok][d]  4.25 KB
    __shared__ __hip_bfloat16 k_s[NTOK][HD + 2];
    __shared__ __hip_bfloat16 v_s[NTOK][HD + 2];
    __shared__ float p_s[NTOK][NTOK + 1];           // scores    16.6 KB
    __shared__ float ao_s[NTOK][HD + 1];            // attn out  8.4 KB

    const int t  = threadIdx.x;
    const int px = t & 63;                 // token within window
    const int g  = t >> 6;                 // 0..7 (wave id)
    const int gu = __builtin_amdgcn_readfirstlane(g);  // provably wave-uniform
    const int b  = blockIdx.z;
    const int y0 = blockIdx.y * WS;
    const int x0 = blockIdx.x * WS;
    const int py = px >> 3, pxx = px & 7;

    // ---- phase 1: stage x tile (64 px x 256 ch) ----
    {
        const float* xb = x + ((long)b * DIMC) * (HRES * HRES)
                            + (long)(y0 + py) * HRES + (x0 + pxx);
        #pragma unroll
        for (int i = 0; i < DIMC / 8; ++i) {
            int c = i * 8 + g;
            x_s[c][px] = __float2bfloat16(xb[(long)c * (HRES * HRES)]);
        }
    }

    float facc[32];
    #pragma unroll
    for (int i = 0; i < 32; ++i) facc[i] = 0.f;

    __syncthreads();

    const float scale = 0.17677669529663687f; // 1/sqrt(32)

    for (int h = 0; h < NH; ++h) {
        // ---- phase 2: QKV for head h. j = gu*12 + i in [0,96); part=j>>5 (q,k,v), d=j&31
        {
            float acc[12];
            #pragma unroll
            for (int i = 0; i < 12; ++i) acc[i] = 0.f;
            const int jbase = gu * 12;
            for (int c0 = 0; c0 < DIMC; c0 += 32) {
                float xv[32];
                #pragma unroll
                for (int cc = 0; cc < 32; ++cc)
                    xv[cc] = __bfloat162float(x_s[c0 + cc][px]);
                #pragma unroll
                for (int i = 0; i < 12; ++i) {
                    int j = jbase + i;
                    int row = (j >> 5) * DIMC + h * HD + (j & 31);
                    const float* wr = w_qkv + (long)row * DIMC + c0;  // wave-uniform -> s_load
                    #pragma unroll
                    for (int cc = 0; cc < 32; ++cc)
                        acc[i] += wr[cc] * xv[cc];
                }
            }
            #pragma unroll
            for (int i = 0; i < 12; ++i) {
                int j = jbase + i;
                int part = j >> 5, d = j & 31;
                __hip_bfloat16 bv = __float2bfloat16(acc[i]);
                if (part == 0)      q_s[px][d] = bv;
                else if (part == 1) k_s[px][d] = bv;
                else                v_s[px][d] = bv;
            }
        }
        __syncthreads();

        // ---- phase 3: scores  s[n][m] = q[n]·k[m] * scale; n=px, m=gu*8+i
        {
            float sc[8];
            #pragma unroll
            for (int i = 0; i < 8; ++i) sc[i] = 0.f;
            #pragma unroll
            for (int d = 0; d < HD; ++d) {
                float qv = __bfloat162float(q_s[px][d]);
                #pragma unroll
                for (int i = 0; i < 8; ++i)
                    sc[i] += __bfloat162float(k_s[gu * 8 + i][d]) * qv;
            }
            #pragma unroll
            for (int i = 0; i < 8; ++i) p_s[px][gu * 8 + i] = sc[i] * scale;
        }
        __syncthreads();

        // ---- phase 4: softmax per row (one thread per row) ----
        if (t < NTOK) {
            float mx = -1e30f;
            #pragma unroll 8
            for (int m = 0; m < NTOK; ++m) mx = fmaxf(mx, p_s[t][m]);
            float sum = 0.f;
            #pragma unroll 8
            for (int m = 0; m < NTOK; ++m) {
                float e = __expf(p_s[t][m] - mx);
                p_s[t][m] = e;
                sum += e;
            }
            float inv = 1.f / sum;
            #pragma unroll 8
            for (int m = 0; m < NTOK; ++m) p_s[t][m] *= inv;
        }
        __syncthreads();

        // ---- phase 5: PV: ao[n][d] = sum_m p[n][m] v[m][d]; n=px, d=gu*4+i
        {
            float ov[4] = {0.f, 0.f, 0.f, 0.f};
            #pragma unroll
            for (int m = 0; m < NTOK; ++m) {
                float pv = p_s[px][m];
                #pragma unroll
                for (int i = 0; i < 4; ++i)
                    ov[i] += __bfloat162float(v_s[m][gu * 4 + i]) * pv;
            }
            #pragma unroll
            for (int i = 0; i < 4; ++i) ao_s[px][gu * 4 + i] = ov[i];
        }
        __syncthreads();

        // ---- phase 6: proj accumulation: facc[i] += W_proj[o, h*32+d] * ao[px][d]
        {
            float av[32];
            #pragma unroll
            for (int d = 0; d < HD; ++d) av[d] = ao_s[px][d];
            #pragma unroll
            for (int i = 0; i < 32; ++i) {
                const float* wr = w_proj + (long)(gu * 32 + i) * DIMC + h * HD; // uniform
                #pragma unroll
                for (int d = 0; d < HD; ++d)
                    facc[i] += wr[d] * av[d];
            }
        }
        __syncthreads();
    }

    // ---- phase 7: write out: o = gu*32 + i, channel-major layout ----
    {
        float* ob = out + ((long)b * DIMC) * (HRES * HRES)
                        + (long)(y0 + py) * HRES + (x0 + pxx);
        #pragma unroll
        for (int i = 0; i < 32; ++i) {
            int o = gu * 32 + i;
            ob[(long)o * (HRES * HRES)] = facc[i];
        }
    }
}

extern "C" void kernel_launch(void* const* d_in, const int* in_sizes, int n_in,
                              void* d_out, int out_size, void* d_ws, size_t ws_size,
                              hipStream_t stream)
{
    const float* x      = (const float*)d_in[0];
    const float* w_qkv  = (const float*)d_in[1];
    const float* w_proj = (const float*)d_in[2];
    float* out          = (float*)d_out;

    dim3 grid(HRES / WS, HRES / WS, 4);   // (32, 32, 4) windows
    dim3 block(512);
    hipLaunchKernelGGL(win_attn_fused, grid, block, 0, stream, x, w_qkv, w_proj, out);
}